// Round 1
// baseline (1325.269 us; speedup 1.0000x reference)
//
#include <hip/hip_runtime.h>
#include <cmath>

#define B_ 2
#define T_ 2048
#define D_ 1024
#define H_ 16
#define HD_ 64
#define M_ (B_ * T_)   // 4096
#define N3_ (3 * D_)   // 3072

// ---------------------------------------------------------------------------
// GEMM 1: qkv = x @ w_qkv^T + b_qkv, scattered to q/k/v in [b,h,t,hd] layout.
// C[i,j] = sum_k A[i,k] * W[j,k]  (both row-major, K contiguous -> coalesced)
// 64x64 tile, TK=16, 256 threads (16x16), 4x4 microtile.
// ---------------------------------------------------------------------------
__global__ __launch_bounds__(256) void gemm_qkv_kernel(
    const float* __restrict__ A, const float* __restrict__ W,
    const float* __restrict__ bias,
    float* __restrict__ q_ws, float* __restrict__ k_ws, float* __restrict__ v_ws)
{
    __shared__ float As[16][64];  // [k][m] — no pad: keeps float4 alignment;
    __shared__ float Bs[16][64];  // compute reads are 2-way at worst (free)
    const int tid = threadIdx.x;
    const int tx = tid & 15, ty = tid >> 4;
    const int m0 = blockIdx.y << 6, n0 = blockIdx.x << 6;
    const int lr = tid >> 2;         // 0..63: tile row loaded by this thread
    const int lk = (tid & 3) << 2;   // 0,4,8,12: k-offset (float4)
    float acc[4][4] = {};

    for (int k0 = 0; k0 < D_; k0 += 16) {
        float4 av = *(const float4*)(A + (size_t)(m0 + lr) * D_ + k0 + lk);
        float4 bv = *(const float4*)(W + (size_t)(n0 + lr) * D_ + k0 + lk);
        As[lk + 0][lr] = av.x; As[lk + 1][lr] = av.y;
        As[lk + 2][lr] = av.z; As[lk + 3][lr] = av.w;
        Bs[lk + 0][lr] = bv.x; Bs[lk + 1][lr] = bv.y;
        Bs[lk + 2][lr] = bv.z; Bs[lk + 3][lr] = bv.w;
        __syncthreads();
#pragma unroll
        for (int kk = 0; kk < 16; ++kk) {
            float4 a = *(const float4*)&As[kk][ty << 2];
            float4 b = *(const float4*)&Bs[kk][tx << 2];
            float ar[4] = {a.x, a.y, a.z, a.w};
            float br[4] = {b.x, b.y, b.z, b.w};
#pragma unroll
            for (int i = 0; i < 4; ++i)
#pragma unroll
                for (int j = 0; j < 4; ++j)
                    acc[i][j] += ar[i] * br[j];
        }
        __syncthreads();
    }

#pragma unroll
    for (int i = 0; i < 4; ++i) {
        int gm = m0 + (ty << 2) + i;
        int bb = gm >> 11;            // / T_
        int tt = gm & (T_ - 1);
#pragma unroll
        for (int j = 0; j < 4; ++j) {
            int gn = n0 + (tx << 2) + j;
            float v = acc[i][j] + bias[gn];
            int which = gn >> 10;           // 0=q 1=k 2=v
            int head  = (gn & 1023) >> 6;
            int dd    = gn & 63;
            float* dst = (which == 0) ? q_ws : (which == 1) ? k_ws : v_ws;
            dst[(((size_t)bb * H_ + head) * T_ + tt) * HD_ + dd] = v;
        }
    }
}

// ---------------------------------------------------------------------------
// GEMM 2: out = o_ws @ w_out^T + b_out  (plain epilogue)
// ---------------------------------------------------------------------------
__global__ __launch_bounds__(256) void gemm_out_kernel(
    const float* __restrict__ A, const float* __restrict__ W,
    const float* __restrict__ bias, float* __restrict__ C)
{
    __shared__ float As[16][64];
    __shared__ float Bs[16][64];
    const int tid = threadIdx.x;
    const int tx = tid & 15, ty = tid >> 4;
    const int m0 = blockIdx.y << 6, n0 = blockIdx.x << 6;
    const int lr = tid >> 2;
    const int lk = (tid & 3) << 2;
    float acc[4][4] = {};

    for (int k0 = 0; k0 < D_; k0 += 16) {
        float4 av = *(const float4*)(A + (size_t)(m0 + lr) * D_ + k0 + lk);
        float4 bv = *(const float4*)(W + (size_t)(n0 + lr) * D_ + k0 + lk);
        As[lk + 0][lr] = av.x; As[lk + 1][lr] = av.y;
        As[lk + 2][lr] = av.z; As[lk + 3][lr] = av.w;
        Bs[lk + 0][lr] = bv.x; Bs[lk + 1][lr] = bv.y;
        Bs[lk + 2][lr] = bv.z; Bs[lk + 3][lr] = bv.w;
        __syncthreads();
#pragma unroll
        for (int kk = 0; kk < 16; ++kk) {
            float4 a = *(const float4*)&As[kk][ty << 2];
            float4 b = *(const float4*)&Bs[kk][tx << 2];
            float ar[4] = {a.x, a.y, a.z, a.w};
            float br[4] = {b.x, b.y, b.z, b.w};
#pragma unroll
            for (int i = 0; i < 4; ++i)
#pragma unroll
                for (int j = 0; j < 4; ++j)
                    acc[i][j] += ar[i] * br[j];
        }
        __syncthreads();
    }

#pragma unroll
    for (int i = 0; i < 4; ++i) {
        int gm = m0 + (ty << 2) + i;
#pragma unroll
        for (int j = 0; j < 4; ++j) {
            int gn = n0 + (tx << 2) + j;
            C[(size_t)gm * D_ + gn] = acc[i][j] + bias[gn];
        }
    }
}

// ---------------------------------------------------------------------------
// Flash-style causal attention.
// Block = (qt, h, b): one 64-row Q tile; iterate K/V tiles kt = 0..qt.
// LDS arrays padded to 65 so inner-loop scalar reads hit distinct banks:
// bank = (row + col) % 32, and microtile rows/cols vary across lanes.
// ---------------------------------------------------------------------------
__global__ __launch_bounds__(256) void attn_kernel(
    const float* __restrict__ q_ws, const float* __restrict__ k_ws,
    const float* __restrict__ v_ws, const float* __restrict__ mask,
    float* __restrict__ o_ws)
{
    __shared__ float Qs[64][65];
    __shared__ float Ks[64][65];
    __shared__ float Vs[64][65];
    __shared__ float Ss[64][65];
    __shared__ float m_s[64], l_s[64], alpha_s[64], kmask[64];

    const int qt = blockIdx.x;
    const int h  = blockIdx.y;
    const int b  = blockIdx.z;
    const int tid = threadIdx.x;
    const int tx = tid & 15, ty = tid >> 4;
    const size_t base = ((size_t)(b * H_ + h)) * T_ * HD_;

    // Load Q tile (pre-scaled by 1/sqrt(hd) = 0.125)
    const float* Qg = q_ws + base + (size_t)(qt << 6) * HD_;
#pragma unroll
    for (int rr = 0; rr < 4; ++rr) {
        int row = (rr << 4) + ty;
        float4 qv = *(const float4*)(Qg + row * HD_ + (tx << 2));
        Qs[row][(tx << 2) + 0] = qv.x * 0.125f;
        Qs[row][(tx << 2) + 1] = qv.y * 0.125f;
        Qs[row][(tx << 2) + 2] = qv.z * 0.125f;
        Qs[row][(tx << 2) + 3] = qv.w * 0.125f;
    }
    if (tid < 64) { m_s[tid] = -INFINITY; l_s[tid] = 0.f; }

    float o[4][4] = {};

    for (int kt = 0; kt <= qt; ++kt) {
        // Load K and V tiles + key mask
        const float* Kg = k_ws + base + (size_t)(kt << 6) * HD_;
        const float* Vg = v_ws + base + (size_t)(kt << 6) * HD_;
#pragma unroll
        for (int rr = 0; rr < 4; ++rr) {
            int row = (rr << 4) + ty;
            float4 kv = *(const float4*)(Kg + row * HD_ + (tx << 2));
            float4 vv = *(const float4*)(Vg + row * HD_ + (tx << 2));
            Ks[row][(tx << 2) + 0] = kv.x; Ks[row][(tx << 2) + 1] = kv.y;
            Ks[row][(tx << 2) + 2] = kv.z; Ks[row][(tx << 2) + 3] = kv.w;
            Vs[row][(tx << 2) + 0] = vv.x; Vs[row][(tx << 2) + 1] = vv.y;
            Vs[row][(tx << 2) + 2] = vv.z; Vs[row][(tx << 2) + 3] = vv.w;
        }
        if (tid < 64) kmask[tid] = mask[(size_t)b * T_ + (kt << 6) + tid];
        __syncthreads();

        // S = Q K^T (microtile 4x4 per thread)
        float s[4][4] = {};
        for (int d = 0; d < 64; ++d) {
            float qv[4], kv[4];
#pragma unroll
            for (int i = 0; i < 4; ++i) qv[i] = Qs[(ty << 2) + i][d];
#pragma unroll
            for (int j = 0; j < 4; ++j) kv[j] = Ks[(tx << 2) + j][d];
#pragma unroll
            for (int i = 0; i < 4; ++i)
#pragma unroll
                for (int j = 0; j < 4; ++j)
                    s[i][j] += qv[i] * kv[j];
        }
        // causal + key-pad mask, write scores
#pragma unroll
        for (int i = 0; i < 4; ++i) {
            int qi = (qt << 6) + (ty << 2) + i;
#pragma unroll
            for (int j = 0; j < 4; ++j) {
                int kj = (kt << 6) + (tx << 2) + j;
                bool ok = (kj <= qi) && (kmask[(tx << 2) + j] != 0.f);
                Ss[(ty << 2) + i][(tx << 2) + j] = ok ? s[i][j] : -INFINITY;
            }
        }
        __syncthreads();

        // Online softmax: one thread per row (wave 0)
        if (tid < 64) {
            float mold = m_s[tid];
            float mx = mold;
            for (int c = 0; c < 64; ++c) mx = fmaxf(mx, Ss[tid][c]);
            float alpha = __expf(mold - mx);   // mold=-inf first tile -> 0
            float rs = 0.f;
            for (int c = 0; c < 64; ++c) {
                float p = __expf(Ss[tid][c] - mx);  // -inf -> 0
                Ss[tid][c] = p;
                rs += p;
            }
            l_s[tid] = l_s[tid] * alpha + rs;
            m_s[tid] = mx;
            alpha_s[tid] = alpha;
        }
        __syncthreads();

        // O = O*alpha + P V
        float al[4];
#pragma unroll
        for (int i = 0; i < 4; ++i) al[i] = alpha_s[(ty << 2) + i];
#pragma unroll
        for (int i = 0; i < 4; ++i)
#pragma unroll
            for (int j = 0; j < 4; ++j) o[i][j] *= al[i];
        for (int kk = 0; kk < 64; ++kk) {
            float p[4], vv[4];
#pragma unroll
            for (int i = 0; i < 4; ++i) p[i] = Ss[(ty << 2) + i][kk];
#pragma unroll
            for (int j = 0; j < 4; ++j) vv[j] = Vs[kk][(tx << 2) + j];
#pragma unroll
            for (int i = 0; i < 4; ++i)
#pragma unroll
                for (int j = 0; j < 4; ++j)
                    o[i][j] += p[i] * vv[j];
        }
        __syncthreads();  // protect Ks/Vs/Ss/kmask before next tile's loads
    }

    // Normalize and write to [b, t, d] layout (d = h*64 + col)
#pragma unroll
    for (int i = 0; i < 4; ++i) {
        float linv = 1.f / l_s[(ty << 2) + i];
        size_t orow = ((size_t)b * T_ + (qt << 6) + (ty << 2) + i) * D_ + h * HD_;
#pragma unroll
        for (int j = 0; j < 4; ++j)
            o_ws[orow + (tx << 2) + j] = o[i][j] * linv;
    }
}

// ---------------------------------------------------------------------------
extern "C" void kernel_launch(void* const* d_in, const int* in_sizes, int n_in,
                              void* d_out, int out_size, void* d_ws, size_t ws_size,
                              hipStream_t stream)
{
    (void)in_sizes; (void)n_in; (void)out_size; (void)ws_size;
    const float* x     = (const float*)d_in[0];
    const float* mask  = (const float*)d_in[1];
    const float* w_qkv = (const float*)d_in[2];
    const float* b_qkv = (const float*)d_in[3];
    const float* w_out = (const float*)d_in[4];
    const float* b_out = (const float*)d_in[5];
    float* out = (float*)d_out;

    const size_t qkv_elems = (size_t)B_ * H_ * T_ * HD_;  // 4M floats each
    float* q_ws = (float*)d_ws;
    float* k_ws = q_ws + qkv_elems;
    float* v_ws = k_ws + qkv_elems;
    float* o_ws = v_ws + qkv_elems;   // [b, t, d]

    gemm_qkv_kernel<<<dim3(N3_ / 64, M_ / 64), 256, 0, stream>>>(
        x, w_qkv, b_qkv, q_ws, k_ws, v_ws);
    attn_kernel<<<dim3(T_ / 64, H_, B_), 256, 0, stream>>>(
        q_ws, k_ws, v_ws, mask, o_ws);
    gemm_out_kernel<<<dim3(D_ / 64, M_ / 64), 256, 0, stream>>>(
        o_ws, w_out, b_out, out);
}

// Round 2
// 283.640 us; speedup vs baseline: 4.6724x; 4.6724x over previous
//
#include <hip/hip_runtime.h>
#include <cmath>

#define B_ 2
#define T_ 2048
#define D_ 1024
#define H_ 16
#define HD_ 64
#define M_ (B_ * T_)   // 4096
#define N3_ (3 * D_)   // 3072
#define K_ 1024

typedef _Float16 halfx8 __attribute__((ext_vector_type(8)));
typedef float f32x4 __attribute__((ext_vector_type(4)));

#define ASYNC_COPY16(gp, lp) \
  __builtin_amdgcn_global_load_lds((__attribute__((address_space(1))) void*)(gp), \
      (__attribute__((address_space(3))) void*)(lp), 16, 0, 0)

// q pre-scale: 1/sqrt(64) * log2(e)  (softmax done in exp2 domain)
#define QSCALE 0.1803368801111204f

// ---------------------------------------------------------------------------
// fp32 -> fp16 conversion, 8 elems/thread
// ---------------------------------------------------------------------------
__global__ __launch_bounds__(256) void f2h_kernel(const float* __restrict__ s,
                                                  _Float16* __restrict__ d, int n)
{
    int i = (blockIdx.x * 256 + threadIdx.x) * 8;
    if (i >= n) return;
    float4 a = *(const float4*)(s + i);
    float4 b = *(const float4*)(s + i + 4);
    halfx8 h;
    h[0] = (_Float16)a.x; h[1] = (_Float16)a.y; h[2] = (_Float16)a.z; h[3] = (_Float16)a.w;
    h[4] = (_Float16)b.x; h[5] = (_Float16)b.y; h[6] = (_Float16)b.z; h[7] = (_Float16)b.w;
    *(halfx8*)(d + i) = h;
}

// ---------------------------------------------------------------------------
// GEMM1: qkv = x @ w_qkv^T + b_qkv (fp16 MFMA, m97 structure)
// 128x128 tile, BK=32, 4 waves, each wave 64x64 (4x4 of 16x16x32 MFMA).
// Epilogue scatters q(scaled)/k to [b,h,t,hd] fp16, v transposed to [b,h,hd,t].
// ---------------------------------------------------------------------------
__global__ __launch_bounds__(256) void gemm_qkv(
    const _Float16* __restrict__ A, const _Float16* __restrict__ Wt,
    const float* __restrict__ bias,
    _Float16* __restrict__ qh, _Float16* __restrict__ kh, _Float16* __restrict__ vth)
{
    __shared__ _Float16 As[128 * 32];
    __shared__ _Float16 Bs[128 * 32];
    const int tid = threadIdx.x;
    const int lane = tid & 63, w = tid >> 6;
    const int col = lane & 15, quad = lane >> 4;
    const int wr = w >> 1, wc = w & 1;
    const int m0 = blockIdx.y << 7, n0 = blockIdx.x << 7;

    const int c0 = w * 2, c1 = c0 + 1;
    const int r0 = c0 * 16 + (lane >> 2), r1 = c1 * 16 + (lane >> 2);
    const int ks = (lane & 3) << 3;

    f32x4 acc[4][4] = {};

    for (int k0 = 0; k0 < K_; k0 += 32) {
        ASYNC_COPY16(A  + (size_t)(m0 + r0) * K_ + k0 + ks, &As[c0 * 512]);
        ASYNC_COPY16(A  + (size_t)(m0 + r1) * K_ + k0 + ks, &As[c1 * 512]);
        ASYNC_COPY16(Wt + (size_t)(n0 + r0) * K_ + k0 + ks, &Bs[c0 * 512]);
        ASYNC_COPY16(Wt + (size_t)(n0 + r1) * K_ + k0 + ks, &Bs[c1 * 512]);
        __syncthreads();
        halfx8 af[4], bf[4];
#pragma unroll
        for (int i = 0; i < 4; ++i)
            af[i] = *(const halfx8*)&As[(wr * 64 + i * 16 + col) * 32 + quad * 8];
#pragma unroll
        for (int j = 0; j < 4; ++j)
            bf[j] = *(const halfx8*)&Bs[(wc * 64 + j * 16 + col) * 32 + quad * 8];
#pragma unroll
        for (int i = 0; i < 4; ++i)
#pragma unroll
            for (int j = 0; j < 4; ++j)
                acc[i][j] = __builtin_amdgcn_mfma_f32_16x16x32_f16(af[i], bf[j], acc[i][j], 0, 0, 0);
        __syncthreads();
    }

#pragma unroll
    for (int i = 0; i < 4; ++i) {
#pragma unroll
        for (int r = 0; r < 4; ++r) {
            int m = m0 + wr * 64 + i * 16 + quad * 4 + r;
            int bb = m >> 11, tt = m & (T_ - 1);
#pragma unroll
            for (int j = 0; j < 4; ++j) {
                int n = n0 + wc * 64 + j * 16 + col;
                float val = acc[i][j][r] + bias[n];
                int which = n >> 10, head = (n >> 6) & 15, dd = n & 63;
                if (which == 0)
                    qh[((size_t)(bb * H_ + head) * T_ + tt) * HD_ + dd] = (_Float16)(val * QSCALE);
                else if (which == 1)
                    kh[((size_t)(bb * H_ + head) * T_ + tt) * HD_ + dd] = (_Float16)val;
                else
                    vth[((size_t)(bb * H_ + head) * HD_ + dd) * T_ + tt] = (_Float16)val;
            }
        }
    }
}

// ---------------------------------------------------------------------------
// GEMM2: out = attn_out @ w_out^T + b_out (fp32 output)
// ---------------------------------------------------------------------------
__global__ __launch_bounds__(256) void gemm_out(
    const _Float16* __restrict__ A, const _Float16* __restrict__ Wt,
    const float* __restrict__ bias, float* __restrict__ C)
{
    __shared__ _Float16 As[128 * 32];
    __shared__ _Float16 Bs[128 * 32];
    const int tid = threadIdx.x;
    const int lane = tid & 63, w = tid >> 6;
    const int col = lane & 15, quad = lane >> 4;
    const int wr = w >> 1, wc = w & 1;
    const int m0 = blockIdx.y << 7, n0 = blockIdx.x << 7;

    const int c0 = w * 2, c1 = c0 + 1;
    const int r0 = c0 * 16 + (lane >> 2), r1 = c1 * 16 + (lane >> 2);
    const int ks = (lane & 3) << 3;

    f32x4 acc[4][4] = {};

    for (int k0 = 0; k0 < K_; k0 += 32) {
        ASYNC_COPY16(A  + (size_t)(m0 + r0) * K_ + k0 + ks, &As[c0 * 512]);
        ASYNC_COPY16(A  + (size_t)(m0 + r1) * K_ + k0 + ks, &As[c1 * 512]);
        ASYNC_COPY16(Wt + (size_t)(n0 + r0) * K_ + k0 + ks, &Bs[c0 * 512]);
        ASYNC_COPY16(Wt + (size_t)(n0 + r1) * K_ + k0 + ks, &Bs[c1 * 512]);
        __syncthreads();
        halfx8 af[4], bf[4];
#pragma unroll
        for (int i = 0; i < 4; ++i)
            af[i] = *(const halfx8*)&As[(wr * 64 + i * 16 + col) * 32 + quad * 8];
#pragma unroll
        for (int j = 0; j < 4; ++j)
            bf[j] = *(const halfx8*)&Bs[(wc * 64 + j * 16 + col) * 32 + quad * 8];
#pragma unroll
        for (int i = 0; i < 4; ++i)
#pragma unroll
            for (int j = 0; j < 4; ++j)
                acc[i][j] = __builtin_amdgcn_mfma_f32_16x16x32_f16(af[i], bf[j], acc[i][j], 0, 0, 0);
        __syncthreads();
    }

#pragma unroll
    for (int i = 0; i < 4; ++i) {
#pragma unroll
        for (int r = 0; r < 4; ++r) {
            int m = m0 + wr * 64 + i * 16 + quad * 4 + r;
#pragma unroll
            for (int j = 0; j < 4; ++j) {
                int n = n0 + wc * 64 + j * 16 + col;
                C[(size_t)m * D_ + n] = acc[i][j][r] + bias[n];
            }
        }
    }
}

// ---------------------------------------------------------------------------
// Flash attention, fp16 MFMA. Block = 256 thr (4 waves), 64-row Q tile.
// Wave w owns q-rows [w*16, w*16+16): softmax state lives in registers,
// row reductions are 16-lane shuffles -> no cross-wave softmax sync.
// LDS rows padded to 72 halfs (144B, 16B-aligned, breaks 128B bank stride).
// P goes C-layout -> LDS (fp16) -> A-layout, wave-private (no barrier).
// ---------------------------------------------------------------------------
__global__ __launch_bounds__(256) void attn_kernel(
    const _Float16* __restrict__ qh, const _Float16* __restrict__ kh,
    const _Float16* __restrict__ vth, const float* __restrict__ mask,
    _Float16* __restrict__ oh)
{
#define LP 72   // padded row stride (halfs)
    __shared__ _Float16 Qs[64 * LP];
    __shared__ _Float16 Ks[64 * LP];
    __shared__ _Float16 Vt[64 * LP];
    __shared__ _Float16 Ps[64 * LP];

    const int qt = (gridDim.x - 1) - blockIdx.x;   // big tiles first
    const int h  = blockIdx.y;
    const int b  = blockIdx.z;
    const int tid = threadIdx.x;
    const int lane = tid & 63, w = tid >> 6;
    const int col = lane & 15, quad = lane >> 4;

    const size_t hb = (size_t)(b * H_ + h);
    const _Float16* qp = qh  + hb * T_ * HD_;
    const _Float16* kp = kh  + hb * T_ * HD_;
    const _Float16* vp = vth + hb * HD_ * T_;
    const float*    mb = mask + (size_t)b * T_;

    // stage Q tile once: 512 chunks of 8 halfs, 2 per thread
    {
        int ch = tid;
#pragma unroll
        for (int u = 0; u < 2; ++u, ch += 256) {
            int row = ch >> 3, seg = ch & 7;
            float4 t4 = *(const float4*)(qp + (size_t)(qt * 64 + row) * HD_ + seg * 8);
            *(float4*)&Qs[row * LP + seg * 8] = t4;
        }
    }
    __syncthreads();
    const halfx8 aq0 = *(const halfx8*)&Qs[(w * 16 + col) * LP + quad * 8];
    const halfx8 aq1 = *(const halfx8*)&Qs[(w * 16 + col) * LP + 32 + quad * 8];

    float mrow[4] = {-INFINITY, -INFINITY, -INFINITY, -INFINITY};
    float lrow[4] = {0.f, 0.f, 0.f, 0.f};
    f32x4 o_acc[4] = {};

    for (int kt = 0; kt <= qt; ++kt) {
        // stage K [key][hd] and V^T [hd][key]
        {
            int ch = tid;
#pragma unroll
            for (int u = 0; u < 2; ++u, ch += 256) {
                int row = ch >> 3, seg = ch & 7;
                float4 kv = *(const float4*)(kp + (size_t)(kt * 64 + row) * HD_ + seg * 8);
                float4 vv = *(const float4*)(vp + (size_t)row * T_ + kt * 64 + seg * 8);
                *(float4*)&Ks[row * LP + seg * 8] = kv;
                *(float4*)&Vt[row * LP + seg * 8] = vv;
            }
        }
        __syncthreads();

        // S strip [16 q x 64 keys] per wave
        f32x4 s[4];
#pragma unroll
        for (int j = 0; j < 4; ++j) {
            f32x4 a = {0.f, 0.f, 0.f, 0.f};
            halfx8 b0 = *(const halfx8*)&Ks[(j * 16 + col) * LP + quad * 8];
            halfx8 b1 = *(const halfx8*)&Ks[(j * 16 + col) * LP + 32 + quad * 8];
            a = __builtin_amdgcn_mfma_f32_16x16x32_f16(aq0, b0, a, 0, 0, 0);
            a = __builtin_amdgcn_mfma_f32_16x16x32_f16(aq1, b1, a, 0, 0, 0);
            s[j] = a;
        }

        // mask + row max
        float mx[4] = {-INFINITY, -INFINITY, -INFINITY, -INFINITY};
#pragma unroll
        for (int j = 0; j < 4; ++j) {
            int k_idx = kt * 64 + j * 16 + col;
            float kmv = mb[k_idx];
#pragma unroll
            for (int r = 0; r < 4; ++r) {
                int q_idx = qt * 64 + w * 16 + quad * 4 + r;
                bool ok = (k_idx <= q_idx) && (kmv != 0.f);
                float sv = ok ? s[j][r] : -INFINITY;
                s[j][r] = sv;
                mx[r] = fmaxf(mx[r], sv);
            }
        }
#pragma unroll
        for (int mm = 1; mm < 16; mm <<= 1)
#pragma unroll
            for (int r = 0; r < 4; ++r)
                mx[r] = fmaxf(mx[r], __shfl_xor(mx[r], mm, 64));

        float alpha[4], rs[4] = {0.f, 0.f, 0.f, 0.f};
#pragma unroll
        for (int r = 0; r < 4; ++r) {
            float mn = fmaxf(mrow[r], mx[r]);
            alpha[r] = exp2f(mrow[r] - mn);
            mrow[r] = mn;
        }
#pragma unroll
        for (int j = 0; j < 4; ++j)
#pragma unroll
            for (int r = 0; r < 4; ++r) {
                float p = exp2f(s[j][r] - mrow[r]);
                s[j][r] = p;
                rs[r] += p;
            }
#pragma unroll
        for (int mm = 1; mm < 16; mm <<= 1)
#pragma unroll
            for (int r = 0; r < 4; ++r)
                rs[r] += __shfl_xor(rs[r], mm, 64);
#pragma unroll
        for (int r = 0; r < 4; ++r) lrow[r] = lrow[r] * alpha[r] + rs[r];

        // rescale O, write P (wave-private rows of Ps)
#pragma unroll
        for (int j = 0; j < 4; ++j)
#pragma unroll
            for (int r = 0; r < 4; ++r) o_acc[j][r] *= alpha[r];
#pragma unroll
        for (int j = 0; j < 4; ++j)
#pragma unroll
            for (int r = 0; r < 4; ++r)
                Ps[(w * 16 + quad * 4 + r) * LP + j * 16 + col] = (_Float16)s[j][r];

        // O += P @ V
        halfx8 ap0 = *(const halfx8*)&Ps[(w * 16 + col) * LP + quad * 8];
        halfx8 ap1 = *(const halfx8*)&Ps[(w * 16 + col) * LP + 32 + quad * 8];
#pragma unroll
        for (int j = 0; j < 4; ++j) {
            halfx8 v0 = *(const halfx8*)&Vt[(j * 16 + col) * LP + quad * 8];
            halfx8 v1 = *(const halfx8*)&Vt[(j * 16 + col) * LP + 32 + quad * 8];
            o_acc[j] = __builtin_amdgcn_mfma_f32_16x16x32_f16(ap0, v0, o_acc[j], 0, 0, 0);
            o_acc[j] = __builtin_amdgcn_mfma_f32_16x16x32_f16(ap1, v1, o_acc[j], 0, 0, 0);
        }
        __syncthreads();   // protect Ks/Vt before next staging
    }

    // normalize + store to [b, t, d] fp16 (consumed by GEMM2)
#pragma unroll
    for (int r = 0; r < 4; ++r) {
        float linv = 1.0f / lrow[r];
        size_t row = (size_t)(b * T_ + qt * 64 + w * 16 + quad * 4 + r) * D_ + h * HD_;
#pragma unroll
        for (int j = 0; j < 4; ++j)
            oh[row + j * 16 + col] = (_Float16)(o_acc[j][r] * linv);
    }
#undef LP
}

// ---------------------------------------------------------------------------
extern "C" void kernel_launch(void* const* d_in, const int* in_sizes, int n_in,
                              void* d_out, int out_size, void* d_ws, size_t ws_size,
                              hipStream_t stream)
{
    (void)in_sizes; (void)n_in; (void)out_size; (void)ws_size;
    const float* x     = (const float*)d_in[0];
    const float* mask  = (const float*)d_in[1];
    const float* w_qkv = (const float*)d_in[2];
    const float* b_qkv = (const float*)d_in[3];
    const float* w_out = (const float*)d_in[4];
    const float* b_out = (const float*)d_in[5];
    float* out = (float*)d_out;

    _Float16* xh  = (_Float16*)d_ws;                    // 4M
    _Float16* wqh = xh  + (size_t)M_ * K_;              // 3M
    _Float16* woh = wqh + (size_t)N3_ * K_;             // 1M
    _Float16* qh  = woh + (size_t)D_ * K_;              // 4M
    _Float16* kh  = qh  + (size_t)M_ * HD_ * H_ / H_ * H_;  // +4M
    _Float16* vth = kh  + (size_t)B_ * H_ * T_ * HD_;   // +4M
    _Float16* oh  = vth + (size_t)B_ * H_ * T_ * HD_;   // +4M

    f2h_kernel<<<(M_ * K_) / 8 / 256, 256, 0, stream>>>(x, xh, M_ * K_);
    f2h_kernel<<<(N3_ * K_) / 8 / 256, 256, 0, stream>>>(w_qkv, wqh, N3_ * K_);
    f2h_kernel<<<(D_ * K_) / 8 / 256, 256, 0, stream>>>(w_out, woh, D_ * K_);

    gemm_qkv<<<dim3(N3_ / 128, M_ / 128), 256, 0, stream>>>(
        xh, wqh, b_qkv, qh, kh, vth);
    attn_kernel<<<dim3(T_ / 64, H_, B_), 256, 0, stream>>>(
        qh, kh, vth, mask, oh);
    gemm_out<<<dim3(D_ / 128, M_ / 128), 256, 0, stream>>>(
        oh, woh, b_out, out);
}

// Round 3
// 260.653 us; speedup vs baseline: 5.0844x; 1.0882x over previous
//
#include <hip/hip_runtime.h>
#include <cmath>

#define B_ 2
#define T_ 2048
#define D_ 1024
#define H_ 16
#define HD_ 64
#define M_ (B_ * T_)   // 4096
#define N3_ (3 * D_)   // 3072
#define K_ 1024

typedef _Float16 halfx8 __attribute__((ext_vector_type(8)));
typedef float f32x4 __attribute__((ext_vector_type(4)));

#define ASYNC_COPY16(gp, lp) \
  __builtin_amdgcn_global_load_lds((__attribute__((address_space(1))) void*)(gp), \
      (__attribute__((address_space(3))) void*)(lp), 16, 0, 0)

// q pre-scale: 1/sqrt(64) * log2(e)  (softmax in exp2 domain)
#define QSCALE 0.1803368801111204f

// ---------------------------------------------------------------------------
__global__ __launch_bounds__(256) void f2h_kernel(const float* __restrict__ s,
                                                  _Float16* __restrict__ d, int n)
{
    int i = (blockIdx.x * 256 + threadIdx.x) * 8;
    if (i >= n) return;
    float4 a = *(const float4*)(s + i);
    float4 b = *(const float4*)(s + i + 4);
    halfx8 h;
    h[0] = (_Float16)a.x; h[1] = (_Float16)a.y; h[2] = (_Float16)a.z; h[3] = (_Float16)a.w;
    h[4] = (_Float16)b.x; h[5] = (_Float16)b.y; h[6] = (_Float16)b.z; h[7] = (_Float16)b.w;
    *(halfx8*)(d + i) = h;
}

// key-pad mask -> additive bias (0 keep, -inf drop)
__global__ __launch_bounds__(256) void mkbias_kernel(const float* __restrict__ mask,
                                                     float* __restrict__ kbias, int n)
{
    int i = blockIdx.x * 256 + threadIdx.x;
    if (i < n) kbias[i] = (mask[i] != 0.f) ? 0.f : -INFINITY;
}

// ---------------------------------------------------------------------------
// GEMM1: qkv = x @ w_qkv^T + b_qkv (fp16 MFMA, 128x128 tile, BK=32).
// Epilogue: q (scaled) -> [b,h,t,hd]; k -> [b,h,t,hd] with hd-seg XOR-swizzle
// by (t&7); v -> [b,h,hd,t] with t-seg (within 64-tiles) XOR-swizzle by (hd&7).
// Swizzles make attn's unpadded LDS ds_read_b128 bank-conflict-free while
// keeping global_load_lds linear-layout compatible.
// ---------------------------------------------------------------------------
__global__ __launch_bounds__(256) void gemm_qkv(
    const _Float16* __restrict__ A, const _Float16* __restrict__ Wt,
    const float* __restrict__ bias,
    _Float16* __restrict__ qh, _Float16* __restrict__ kh, _Float16* __restrict__ vth)
{
    __shared__ _Float16 As[128 * 32];
    __shared__ _Float16 Bs[128 * 32];
    const int tid = threadIdx.x;
    const int lane = tid & 63, w = tid >> 6;
    const int col = lane & 15, quad = lane >> 4;
    const int wr = w >> 1, wc = w & 1;
    const int m0 = blockIdx.y << 7, n0 = blockIdx.x << 7;

    const int c0 = w * 2, c1 = c0 + 1;
    const int r0 = c0 * 16 + (lane >> 2), r1 = c1 * 16 + (lane >> 2);
    const int ks = (lane & 3) << 3;

    f32x4 acc[4][4] = {};

    for (int k0 = 0; k0 < K_; k0 += 32) {
        ASYNC_COPY16(A  + (size_t)(m0 + r0) * K_ + k0 + ks, &As[c0 * 512]);
        ASYNC_COPY16(A  + (size_t)(m0 + r1) * K_ + k0 + ks, &As[c1 * 512]);
        ASYNC_COPY16(Wt + (size_t)(n0 + r0) * K_ + k0 + ks, &Bs[c0 * 512]);
        ASYNC_COPY16(Wt + (size_t)(n0 + r1) * K_ + k0 + ks, &Bs[c1 * 512]);
        __syncthreads();
        halfx8 af[4], bf[4];
#pragma unroll
        for (int i = 0; i < 4; ++i)
            af[i] = *(const halfx8*)&As[(wr * 64 + i * 16 + col) * 32 + quad * 8];
#pragma unroll
        for (int j = 0; j < 4; ++j)
            bf[j] = *(const halfx8*)&Bs[(wc * 64 + j * 16 + col) * 32 + quad * 8];
#pragma unroll
        for (int i = 0; i < 4; ++i)
#pragma unroll
            for (int j = 0; j < 4; ++j)
                acc[i][j] = __builtin_amdgcn_mfma_f32_16x16x32_f16(af[i], bf[j], acc[i][j], 0, 0, 0);
        __syncthreads();
    }

#pragma unroll
    for (int i = 0; i < 4; ++i) {
#pragma unroll
        for (int r = 0; r < 4; ++r) {
            int m = m0 + wr * 64 + i * 16 + quad * 4 + r;
            int bb = m >> 11, tt = m & (T_ - 1);
#pragma unroll
            for (int j = 0; j < 4; ++j) {
                int n = n0 + wc * 64 + j * 16 + col;
                float val = acc[i][j][r] + bias[n];
                int which = n >> 10, head = (n >> 6) & 15, dd = n & 63;
                if (which == 0) {
                    qh[((size_t)(bb * H_ + head) * T_ + tt) * HD_ + dd] = (_Float16)(val * QSCALE);
                } else if (which == 1) {
                    int dds = ((((dd >> 3) ^ (tt & 7)) & 7) << 3) | (dd & 7);
                    kh[((size_t)(bb * H_ + head) * T_ + tt) * HD_ + dds] = (_Float16)val;
                } else {
                    int tts = (tt & ~63) | (((((tt >> 3) & 7) ^ (dd & 7)) & 7) << 3) | (tt & 7);
                    vth[((size_t)(bb * H_ + head) * HD_ + dd) * T_ + tts] = (_Float16)val;
                }
            }
        }
    }
}

// ---------------------------------------------------------------------------
// GEMM2: out = attn_out @ w_out^T + b_out (fp32 output)
// ---------------------------------------------------------------------------
__global__ __launch_bounds__(256) void gemm_out(
    const _Float16* __restrict__ A, const _Float16* __restrict__ Wt,
    const float* __restrict__ bias, float* __restrict__ C)
{
    __shared__ _Float16 As[128 * 32];
    __shared__ _Float16 Bs[128 * 32];
    const int tid = threadIdx.x;
    const int lane = tid & 63, w = tid >> 6;
    const int col = lane & 15, quad = lane >> 4;
    const int wr = w >> 1, wc = w & 1;
    const int m0 = blockIdx.y << 7, n0 = blockIdx.x << 7;

    const int c0 = w * 2, c1 = c0 + 1;
    const int r0 = c0 * 16 + (lane >> 2), r1 = c1 * 16 + (lane >> 2);
    const int ks = (lane & 3) << 3;

    f32x4 acc[4][4] = {};

    for (int k0 = 0; k0 < K_; k0 += 32) {
        ASYNC_COPY16(A  + (size_t)(m0 + r0) * K_ + k0 + ks, &As[c0 * 512]);
        ASYNC_COPY16(A  + (size_t)(m0 + r1) * K_ + k0 + ks, &As[c1 * 512]);
        ASYNC_COPY16(Wt + (size_t)(n0 + r0) * K_ + k0 + ks, &Bs[c0 * 512]);
        ASYNC_COPY16(Wt + (size_t)(n0 + r1) * K_ + k0 + ks, &Bs[c1 * 512]);
        __syncthreads();
        halfx8 af[4], bf[4];
#pragma unroll
        for (int i = 0; i < 4; ++i)
            af[i] = *(const halfx8*)&As[(wr * 64 + i * 16 + col) * 32 + quad * 8];
#pragma unroll
        for (int j = 0; j < 4; ++j)
            bf[j] = *(const halfx8*)&Bs[(wc * 64 + j * 16 + col) * 32 + quad * 8];
#pragma unroll
        for (int i = 0; i < 4; ++i)
#pragma unroll
            for (int j = 0; j < 4; ++j)
                acc[i][j] = __builtin_amdgcn_mfma_f32_16x16x32_f16(af[i], bf[j], acc[i][j], 0, 0, 0);
        __syncthreads();
    }

#pragma unroll
    for (int i = 0; i < 4; ++i) {
#pragma unroll
        for (int r = 0; r < 4; ++r) {
            int m = m0 + wr * 64 + i * 16 + quad * 4 + r;
#pragma unroll
            for (int j = 0; j < 4; ++j) {
                int n = n0 + wc * 64 + j * 16 + col;
                C[(size_t)m * D_ + n] = acc[i][j][r] + bias[n];
            }
        }
    }
}

// ---------------------------------------------------------------------------
// Flash attention v3. 256 thr / 4 waves; Q-tile 128 rows, 32 per wave
// (2 strips of 16). 64 keys/iter, K/V double-buffered via global_load_lds,
// one barrier per iter. Row-sum via ones-column MFMA (V^T row 64 = 1).
// Interior tiles skip causal compare; key-pad mask is an additive bias.
// K/V LDS rows unpadded (128B) but seg-XOR-swizzled -> conflict-free b128.
// ---------------------------------------------------------------------------
__global__ __launch_bounds__(256) void attn_kernel(
    const _Float16* __restrict__ qh, const _Float16* __restrict__ kh,
    const _Float16* __restrict__ vth, const float* __restrict__ kbias,
    _Float16* __restrict__ oh)
{
    __shared__ _Float16 Ks[2][64 * 64];
    __shared__ _Float16 Vt[2][80 * 64];   // rows 64..79: ones-row + zeros
    __shared__ _Float16 Ps[128 * 72];     // padded (144B rows): 2-way max

    const int qt = (int)(gridDim.x - 1) - (int)blockIdx.x;  // big blocks first
    const int h = blockIdx.y, b = blockIdx.z;
    const int tid = threadIdx.x;
    const int lane = tid & 63, w = tid >> 6;
    const int col = lane & 15, quad = lane >> 4;

    const size_t hb = (size_t)(b * H_ + h);
    const _Float16* qp = qh + hb * T_ * HD_;
    const _Float16* kp = kh + hb * T_ * HD_;
    const _Float16* vp = vth + hb * HD_ * T_;
    const float* kb = kbias + (size_t)b * T_;

    // static ones/zero rows for both V buffers (row 64 = 1.0, 65..79 = 0)
    for (int idx = tid; idx < 2 * 16 * 64; idx += 256) {
        int buf = idx >> 10, off = idx & 1023;
        Vt[buf][64 * 64 + off] = (off < 64) ? (_Float16)1.0f : (_Float16)0.0f;
    }

    // Q fragments -> registers (A-layout: m=col, k=quad*8+j (+32))
    halfx8 aq[2][2];
#pragma unroll
    for (int st = 0; st < 2; ++st)
#pragma unroll
        for (int kk = 0; kk < 2; ++kk)
            aq[st][kk] = *(const halfx8*)(qp +
                (size_t)(qt * 128 + w * 32 + st * 16 + col) * HD_ + kk * 32 + quad * 8);

    const int seg0 = (quad ^ (col & 7)) << 3;  // swizzled frag offset (halfs)
    const int seg1 = seg0 ^ 32;

    float mrow[2][4];
#pragma unroll
    for (int st = 0; st < 2; ++st)
#pragma unroll
        for (int r = 0; r < 4; ++r) mrow[st][r] = -INFINITY;
    f32x4 o_acc[2][5] = {};   // j=4 column: running row-sum l

    const int ktmax = 2 * qt + 1;

    // prologue: stage tile 0 into buffer 0
    {
        const _Float16* ksrc = kp + (size_t)(w * 16) * HD_;
        ASYNC_COPY16(ksrc + lane * 8, &Ks[0][(w * 16) * 64]);
        ASYNC_COPY16(ksrc + 8 * HD_ + lane * 8, &Ks[0][(w * 16 + 8) * 64]);
        const _Float16* vsrc = vp + (size_t)(w * 16 + (lane >> 3)) * T_ + (lane & 7) * 8;
        ASYNC_COPY16(vsrc, &Vt[0][(w * 16) * 64]);
        ASYNC_COPY16(vsrc + 8 * T_, &Vt[0][(w * 16 + 8) * 64]);
    }

    for (int kt = 0; kt <= ktmax; ++kt) {
        const int cur = kt & 1;
        __syncthreads();   // drains async copies for tile kt; prev reads done
        if (kt < ktmax) {  // prefetch next tile into other buffer
            const int nb = cur ^ 1;
            const _Float16* ksrc = kp + (size_t)((kt + 1) * 64 + w * 16) * HD_;
            ASYNC_COPY16(ksrc + lane * 8, &Ks[nb][(w * 16) * 64]);
            ASYNC_COPY16(ksrc + 8 * HD_ + lane * 8, &Ks[nb][(w * 16 + 8) * 64]);
            const _Float16* vsrc = vp + (size_t)(w * 16 + (lane >> 3)) * T_
                                     + (kt + 1) * 64 + (lane & 7) * 8;
            ASYNC_COPY16(vsrc, &Vt[nb][(w * 16) * 64]);
            ASYNC_COPY16(vsrc + 8 * T_, &Vt[nb][(w * 16 + 8) * 64]);
        }

        float kbv[4];
#pragma unroll
        for (int j = 0; j < 4; ++j) kbv[j] = kb[kt * 64 + j * 16 + col];

        // S = Q K^T  (K-frag reused across both q-strips)
        f32x4 s[2][4];
#pragma unroll
        for (int j = 0; j < 4; ++j) {
            const _Float16* krow = &Ks[cur][(j * 16 + col) * 64];
            halfx8 b0 = *(const halfx8*)(krow + seg0);
            halfx8 b1 = *(const halfx8*)(krow + seg1);
#pragma unroll
            for (int st = 0; st < 2; ++st) {
                f32x4 a = {0.f, 0.f, 0.f, 0.f};
                a = __builtin_amdgcn_mfma_f32_16x16x32_f16(aq[st][0], b0, a, 0, 0, 0);
                a = __builtin_amdgcn_mfma_f32_16x16x32_f16(aq[st][1], b1, a, 0, 0, 0);
                s[st][j] = a;
            }
        }

        // running max on raw scores (valid upper bound; bias only 0/-inf)
        float alpha[2][4];
#pragma unroll
        for (int st = 0; st < 2; ++st) {
            float mx[4];
#pragma unroll
            for (int r = 0; r < 4; ++r)
                mx[r] = fmaxf(fmaxf(s[st][0][r], s[st][1][r]),
                              fmaxf(s[st][2][r], s[st][3][r]));
#pragma unroll
            for (int mm = 1; mm < 16; mm <<= 1)
#pragma unroll
                for (int r = 0; r < 4; ++r)
                    mx[r] = fmaxf(mx[r], __shfl_xor(mx[r], mm, 64));
#pragma unroll
            for (int r = 0; r < 4; ++r) {
                float mn = fmaxf(mrow[st][r], mx[r]);
                alpha[st][r] = exp2f(mrow[st][r] - mn);
                mrow[st][r] = mn;
            }
        }

        // P = exp2(s + bias - m) -> LDS (wave-private rows, no barrier)
        if (kt >= 2 * qt) {   // diagonal tiles: causal compare needed
#pragma unroll
            for (int st = 0; st < 2; ++st)
#pragma unroll
                for (int j = 0; j < 4; ++j) {
                    int k_idx = kt * 64 + j * 16 + col;
#pragma unroll
                    for (int r = 0; r < 4; ++r) {
                        int q_idx = qt * 128 + w * 32 + st * 16 + quad * 4 + r;
                        float bb2 = (k_idx <= q_idx) ? kbv[j] : -INFINITY;
                        float p = exp2f(s[st][j][r] + bb2 - mrow[st][r]);
                        Ps[(w * 32 + st * 16 + quad * 4 + r) * 72 + j * 16 + col] = (_Float16)p;
                    }
                }
        } else {              // interior: no causal compare
#pragma unroll
            for (int st = 0; st < 2; ++st)
#pragma unroll
                for (int j = 0; j < 4; ++j)
#pragma unroll
                    for (int r = 0; r < 4; ++r) {
                        float p = exp2f(s[st][j][r] + kbv[j] - mrow[st][r]);
                        Ps[(w * 32 + st * 16 + quad * 4 + r) * 72 + j * 16 + col] = (_Float16)p;
                    }
        }

        // rescale accumulators (incl. sum column)
#pragma unroll
        for (int st = 0; st < 2; ++st)
#pragma unroll
            for (int j = 0; j < 5; ++j)
#pragma unroll
                for (int r = 0; r < 4; ++r)
                    o_acc[st][j][r] *= alpha[st][r];

        // O += P V  (V-frag reused across strips; j=4 = ones column -> l)
        halfx8 ap[2][2];
#pragma unroll
        for (int st = 0; st < 2; ++st) {
            ap[st][0] = *(const halfx8*)&Ps[(w * 32 + st * 16 + col) * 72 + quad * 8];
            ap[st][1] = *(const halfx8*)&Ps[(w * 32 + st * 16 + col) * 72 + 32 + quad * 8];
        }
#pragma unroll
        for (int j = 0; j < 5; ++j) {
            const _Float16* vrow = &Vt[cur][(j * 16 + col) * 64];
            halfx8 v0 = *(const halfx8*)(vrow + seg0);
            halfx8 v1 = *(const halfx8*)(vrow + seg1);
#pragma unroll
            for (int st = 0; st < 2; ++st) {
                o_acc[st][j] = __builtin_amdgcn_mfma_f32_16x16x32_f16(ap[st][0], v0, o_acc[st][j], 0, 0, 0);
                o_acc[st][j] = __builtin_amdgcn_mfma_f32_16x16x32_f16(ap[st][1], v1, o_acc[st][j], 0, 0, 0);
            }
        }
    }

    // epilogue: l lives at col 0 of each quad (lane quad*16); broadcast + store
#pragma unroll
    for (int st = 0; st < 2; ++st)
#pragma unroll
        for (int r = 0; r < 4; ++r) {
            float l = __shfl(o_acc[st][4][r], lane & 48, 64);
            float linv = 1.0f / l;
            size_t row = (size_t)(b * T_ + qt * 128 + w * 32 + st * 16 + quad * 4 + r) * D_ + h * HD_;
#pragma unroll
            for (int j = 0; j < 4; ++j)
                oh[row + j * 16 + col] = (_Float16)(o_acc[st][j][r] * linv);
        }
}

// ---------------------------------------------------------------------------
extern "C" void kernel_launch(void* const* d_in, const int* in_sizes, int n_in,
                              void* d_out, int out_size, void* d_ws, size_t ws_size,
                              hipStream_t stream)
{
    (void)in_sizes; (void)n_in; (void)out_size; (void)ws_size;
    const float* x     = (const float*)d_in[0];
    const float* mask  = (const float*)d_in[1];
    const float* w_qkv = (const float*)d_in[2];
    const float* b_qkv = (const float*)d_in[3];
    const float* w_out = (const float*)d_in[4];
    const float* b_out = (const float*)d_in[5];
    float* out = (float*)d_out;

    const size_t QKV1 = (size_t)B_ * H_ * T_ * HD_;   // 4M halfs
    _Float16* xh  = (_Float16*)d_ws;                  // 4M
    _Float16* wqh = xh  + (size_t)M_ * K_;            // 3M
    _Float16* woh = wqh + (size_t)N3_ * K_;           // 1M
    _Float16* qh  = woh + (size_t)D_ * K_;            // 4M
    _Float16* kh  = qh  + QKV1;                       // 4M
    _Float16* vth = kh  + QKV1;                       // 4M
    _Float16* oh  = vth + QKV1;                       // 4M
    float* kbias  = (float*)(oh + QKV1);              // 4096 floats

    f2h_kernel<<<(M_ * K_) / 8 / 256, 256, 0, stream>>>(x, xh, M_ * K_);
    f2h_kernel<<<(N3_ * K_) / 8 / 256, 256, 0, stream>>>(w_qkv, wqh, N3_ * K_);
    f2h_kernel<<<(D_ * K_) / 8 / 256, 256, 0, stream>>>(w_out, woh, D_ * K_);
    mkbias_kernel<<<(B_ * T_ + 255) / 256, 256, 0, stream>>>(mask, kbias, B_ * T_);

    gemm_qkv<<<dim3(N3_ / 128, M_ / 128), 256, 0, stream>>>(
        xh, wqh, b_qkv, qh, kh, vth);
    attn_kernel<<<dim3(T_ / 128, H_, B_), 256, 0, stream>>>(
        qh, kh, vth, kbias, oh);
    gemm_out<<<dim3(D_ / 128, M_ / 128), 256, 0, stream>>>(
        oh, woh, b_out, out);
}

// Round 4
// 242.295 us; speedup vs baseline: 5.4697x; 1.0758x over previous
//
#include <hip/hip_runtime.h>
#include <cmath>

#define B_ 2
#define T_ 2048
#define D_ 1024
#define H_ 16
#define HD_ 64
#define M_ (B_ * T_)   // 4096
#define N3_ (3 * D_)   // 3072
#define K_ 1024

typedef _Float16 halfx8 __attribute__((ext_vector_type(8)));
typedef _Float16 halfx4 __attribute__((ext_vector_type(4)));
typedef float f32x4 __attribute__((ext_vector_type(4)));
typedef float f32x16 __attribute__((ext_vector_type(16)));

#define ASYNC_COPY16(gp, lp) \
  __builtin_amdgcn_global_load_lds((__attribute__((address_space(1))) void*)(gp), \
      (__attribute__((address_space(3))) void*)(lp), 16, 0, 0)

// q pre-scale: 1/sqrt(64) * log2(e)  (softmax in exp2 domain)
#define QSCALE 0.1803368801111204f

// ---------------------------------------------------------------------------
__global__ __launch_bounds__(256) void f2h_kernel(const float* __restrict__ s,
                                                  _Float16* __restrict__ d, int n)
{
    int i = (blockIdx.x * 256 + threadIdx.x) * 8;
    if (i >= n) return;
    float4 a = *(const float4*)(s + i);
    float4 b = *(const float4*)(s + i + 4);
    halfx8 h;
    h[0] = (_Float16)a.x; h[1] = (_Float16)a.y; h[2] = (_Float16)a.z; h[3] = (_Float16)a.w;
    h[4] = (_Float16)b.x; h[5] = (_Float16)b.y; h[6] = (_Float16)b.z; h[7] = (_Float16)b.w;
    *(halfx8*)(d + i) = h;
}

// tile flags init (1 = all keys kept in that 64-key tile)
__global__ void initflags_kernel(int* __restrict__ tflags)
{
    tflags[threadIdx.x] = 1;
}

// key-pad mask -> additive bias (0 keep, -inf drop) + per-64-tile flags
__global__ __launch_bounds__(256) void mkbias_kernel(const float* __restrict__ mask,
                                                     float* __restrict__ kbias,
                                                     int* __restrict__ tflags, int n)
{
    int i = blockIdx.x * 256 + threadIdx.x;
    if (i < n) {
        float mv = mask[i];
        kbias[i] = (mv != 0.f) ? 0.f : -INFINITY;
        if (mv == 0.f) tflags[i >> 6] = 0;   // benign race: all writers store 0
    }
}

// ---------------------------------------------------------------------------
// GEMM1: qkv = x @ w_qkv^T + b_qkv (fp16 MFMA, 128x128 tile, BK=32).
// Epilogue: q (scaled) -> [b,h,t,hd]; k -> [b,h,t,hd] with hd-seg XOR-swizzle
// by (t&7); v -> [b,h,hd,t] with t-seg (within 64-tiles) XOR-swizzle by (hd&7).
// ---------------------------------------------------------------------------
__global__ __launch_bounds__(256) void gemm_qkv(
    const _Float16* __restrict__ A, const _Float16* __restrict__ Wt,
    const float* __restrict__ bias,
    _Float16* __restrict__ qh, _Float16* __restrict__ kh, _Float16* __restrict__ vth)
{
    __shared__ _Float16 As[128 * 32];
    __shared__ _Float16 Bs[128 * 32];
    const int tid = threadIdx.x;
    const int lane = tid & 63, w = tid >> 6;
    const int col = lane & 15, quad = lane >> 4;
    const int wr = w >> 1, wc = w & 1;
    const int m0 = blockIdx.y << 7, n0 = blockIdx.x << 7;

    const int c0 = w * 2, c1 = c0 + 1;
    const int r0 = c0 * 16 + (lane >> 2), r1 = c1 * 16 + (lane >> 2);
    const int ks = (lane & 3) << 3;

    f32x4 acc[4][4] = {};

    for (int k0 = 0; k0 < K_; k0 += 32) {
        ASYNC_COPY16(A  + (size_t)(m0 + r0) * K_ + k0 + ks, &As[c0 * 512]);
        ASYNC_COPY16(A  + (size_t)(m0 + r1) * K_ + k0 + ks, &As[c1 * 512]);
        ASYNC_COPY16(Wt + (size_t)(n0 + r0) * K_ + k0 + ks, &Bs[c0 * 512]);
        ASYNC_COPY16(Wt + (size_t)(n0 + r1) * K_ + k0 + ks, &Bs[c1 * 512]);
        __syncthreads();
        halfx8 af[4], bf[4];
#pragma unroll
        for (int i = 0; i < 4; ++i)
            af[i] = *(const halfx8*)&As[(wr * 64 + i * 16 + col) * 32 + quad * 8];
#pragma unroll
        for (int j = 0; j < 4; ++j)
            bf[j] = *(const halfx8*)&Bs[(wc * 64 + j * 16 + col) * 32 + quad * 8];
#pragma unroll
        for (int i = 0; i < 4; ++i)
#pragma unroll
            for (int j = 0; j < 4; ++j)
                acc[i][j] = __builtin_amdgcn_mfma_f32_16x16x32_f16(af[i], bf[j], acc[i][j], 0, 0, 0);
        __syncthreads();
    }

#pragma unroll
    for (int i = 0; i < 4; ++i) {
#pragma unroll
        for (int r = 0; r < 4; ++r) {
            int m = m0 + wr * 64 + i * 16 + quad * 4 + r;
            int bb = m >> 11, tt = m & (T_ - 1);
#pragma unroll
            for (int j = 0; j < 4; ++j) {
                int n = n0 + wc * 64 + j * 16 + col;
                float val = acc[i][j][r] + bias[n];
                int which = n >> 10, head = (n >> 6) & 15, dd = n & 63;
                if (which == 0) {
                    qh[((size_t)(bb * H_ + head) * T_ + tt) * HD_ + dd] = (_Float16)(val * QSCALE);
                } else if (which == 1) {
                    int dds = ((((dd >> 3) ^ (tt & 7)) & 7) << 3) | (dd & 7);
                    kh[((size_t)(bb * H_ + head) * T_ + tt) * HD_ + dds] = (_Float16)val;
                } else {
                    int tts = (tt & ~63) | (((((tt >> 3) & 7) ^ (dd & 7)) & 7) << 3) | (tt & 7);
                    vth[((size_t)(bb * H_ + head) * HD_ + dd) * T_ + tts] = (_Float16)val;
                }
            }
        }
    }
}

// ---------------------------------------------------------------------------
// GEMM2: out = attn_out @ w_out^T + b_out (fp32 output)
// ---------------------------------------------------------------------------
__global__ __launch_bounds__(256) void gemm_out(
    const _Float16* __restrict__ A, const _Float16* __restrict__ Wt,
    const float* __restrict__ bias, float* __restrict__ C)
{
    __shared__ _Float16 As[128 * 32];
    __shared__ _Float16 Bs[128 * 32];
    const int tid = threadIdx.x;
    const int lane = tid & 63, w = tid >> 6;
    const int col = lane & 15, quad = lane >> 4;
    const int wr = w >> 1, wc = w & 1;
    const int m0 = blockIdx.y << 7, n0 = blockIdx.x << 7;

    const int c0 = w * 2, c1 = c0 + 1;
    const int r0 = c0 * 16 + (lane >> 2), r1 = c1 * 16 + (lane >> 2);
    const int ks = (lane & 3) << 3;

    f32x4 acc[4][4] = {};

    for (int k0 = 0; k0 < K_; k0 += 32) {
        ASYNC_COPY16(A  + (size_t)(m0 + r0) * K_ + k0 + ks, &As[c0 * 512]);
        ASYNC_COPY16(A  + (size_t)(m0 + r1) * K_ + k0 + ks, &As[c1 * 512]);
        ASYNC_COPY16(Wt + (size_t)(n0 + r0) * K_ + k0 + ks, &Bs[c0 * 512]);
        ASYNC_COPY16(Wt + (size_t)(n0 + r1) * K_ + k0 + ks, &Bs[c1 * 512]);
        __syncthreads();
        halfx8 af[4], bf[4];
#pragma unroll
        for (int i = 0; i < 4; ++i)
            af[i] = *(const halfx8*)&As[(wr * 64 + i * 16 + col) * 32 + quad * 8];
#pragma unroll
        for (int j = 0; j < 4; ++j)
            bf[j] = *(const halfx8*)&Bs[(wc * 64 + j * 16 + col) * 32 + quad * 8];
#pragma unroll
        for (int i = 0; i < 4; ++i)
#pragma unroll
            for (int j = 0; j < 4; ++j)
                acc[i][j] = __builtin_amdgcn_mfma_f32_16x16x32_f16(af[i], bf[j], acc[i][j], 0, 0, 0);
        __syncthreads();
    }

#pragma unroll
    for (int i = 0; i < 4; ++i) {
#pragma unroll
        for (int r = 0; r < 4; ++r) {
            int m = m0 + wr * 64 + i * 16 + quad * 4 + r;
#pragma unroll
            for (int j = 0; j < 4; ++j) {
                int n = n0 + wc * 64 + j * 16 + col;
                C[(size_t)m * D_ + n] = acc[i][j][r] + bias[n];
            }
        }
    }
}

// ---------------------------------------------------------------------------
// Flash attention v4: transposed-S scheme, 32x32 MFMA shapes.
// 4 waves x 32 q-rows = 128-row Q tile; 64 keys/iter, K/V double-buffered
// (32 KB LDS total). S^T = K·Q^T via mfma_32x32x16 (operand swap); its C-regs
// pack DIRECTLY into B-frags of mfma_32x32x8 for O^T = V^T·P^T — P never
// touches LDS. Softmax reductions: single shfl_xor(32). Row-sum in-register.
// Causal: per-wave skip of fully-masked tiles; reg-level select on diagonal.
// Key-pad mask: per-64-tile all-keep flags (uniform branch), slow path adds
// additive bias from global.
// ---------------------------------------------------------------------------
__global__ __launch_bounds__(256) void attn_kernel(
    const _Float16* __restrict__ qh, const _Float16* __restrict__ kh,
    const _Float16* __restrict__ vth, const float* __restrict__ kbias,
    const int* __restrict__ tflags, _Float16* __restrict__ oh)
{
    __shared__ _Float16 Ks[2][64 * 64];
    __shared__ _Float16 Vt[2][64 * 64];

    const int qt = 15 - (int)blockIdx.x;       // big tiles dispatched first
    const int h = blockIdx.y, b = blockIdx.z;
    const int tid = threadIdx.x;
    const int lane = tid & 63, w = tid >> 6;
    const int l31 = lane & 31, q2 = lane >> 5;

    const size_t hb = (size_t)(b * H_ + h);
    const _Float16* qp = qh + hb * T_ * HD_;
    const _Float16* kp = kh + hb * T_ * HD_;
    const _Float16* vp = vth + hb * HD_ * T_;
    const float* kb = kbias + (size_t)b * T_;
    const int* tf = tflags + b * 32;

    const int q_row = qt * 128 + w * 32 + l31;   // this lane's query row

    // Q B-frags (global, unswizzled): B[n=q=lane&31][k=hc*16+q2*8+j]
    halfx8 bq[4];
#pragma unroll
    for (int hc = 0; hc < 4; ++hc)
        bq[hc] = *(const halfx8*)(qp + (size_t)q_row * HD_ + hc * 16 + q2 * 8);

    float mrow = -INFINITY, lrow = 0.f;
    f32x16 oacc[2] = {};

    // prologue: stage tile 0 into buffer 0
    {
        const _Float16* ksrc = kp + (size_t)(w * 16) * HD_;
        ASYNC_COPY16(ksrc + lane * 8, &Ks[0][(w * 16) * 64]);
        ASYNC_COPY16(ksrc + 8 * HD_ + lane * 8, &Ks[0][(w * 16 + 8) * 64]);
        const _Float16* vsrc = vp + (size_t)(w * 16 + (lane >> 3)) * T_ + (lane & 7) * 8;
        ASYNC_COPY16(vsrc, &Vt[0][(w * 16) * 64]);
        ASYNC_COPY16(vsrc + 8 * T_, &Vt[0][(w * 16 + 8) * 64]);
    }

    const int ktmax = 2 * qt + 1;
    for (int kt = 0; kt <= ktmax; ++kt) {
        const int cur = kt & 1;
        __syncthreads();   // drains async copies for tile kt
        if (kt < ktmax) {  // prefetch next tile into other buffer
            const int nb = cur ^ 1;
            const _Float16* ksrc = kp + (size_t)((kt + 1) * 64 + w * 16) * HD_;
            ASYNC_COPY16(ksrc + lane * 8, &Ks[nb][(w * 16) * 64]);
            ASYNC_COPY16(ksrc + 8 * HD_ + lane * 8, &Ks[nb][(w * 16 + 8) * 64]);
            const _Float16* vsrc = vp + (size_t)(w * 16 + (lane >> 3)) * T_
                                     + (kt + 1) * 64 + (lane & 7) * 8;
            ASYNC_COPY16(vsrc, &Vt[nb][(w * 16) * 64]);
            ASYNC_COPY16(vsrc + 8 * T_, &Vt[nb][(w * 16 + 8) * 64]);
        }
        // wave-uniform: no valid keys for this wave's q-strip -> skip compute
        if (kt * 64 > qt * 128 + w * 32 + 31) continue;

        // S^T = K·Q^T : A = K rows (swizzled LDS), B = Q regs
        f32x16 sa[2];
#pragma unroll
        for (int kb2 = 0; kb2 < 2; ++kb2) {
            f32x16 a;
#pragma unroll
            for (int r = 0; r < 16; ++r) a[r] = 0.f;
#pragma unroll
            for (int hc = 0; hc < 4; ++hc) {
                int seg = (hc * 2 + q2) ^ (l31 & 7);
                halfx8 ka = *(const halfx8*)&Ks[cur][(kb2 * 32 + l31) * 64 + seg * 8];
                a = __builtin_amdgcn_mfma_f32_32x32x16_f16(ka, bq[hc], a, 0, 0, 0);
            }
            sa[kb2] = a;
        }

        // running max on raw scores (upper bound; bias only 0/-inf)
        float mx = sa[0][0];
#pragma unroll
        for (int r = 1; r < 16; ++r) mx = fmaxf(mx, sa[0][r]);
#pragma unroll
        for (int r = 0; r < 16; ++r) mx = fmaxf(mx, sa[1][r]);
        mx = fmaxf(mx, __shfl_xor(mx, 32, 64));
        float mnew = fmaxf(mrow, mx);
        float alpha = exp2f(mrow - mnew);
        mrow = mnew;

        // P = exp2(s [+bias] - m), packed straight into 32x32x8 B-frags
        const bool interior = (kt * 64 + 63 <= qt * 128 + w * 32);  // wave-uniform
        const int allkeep = tf[kt];
        halfx4 pf[2][4];
        float rsum = 0.f;
        if (interior && allkeep) {
#pragma unroll
            for (int kb2 = 0; kb2 < 2; ++kb2)
#pragma unroll
                for (int c = 0; c < 4; ++c)
#pragma unroll
                    for (int j = 0; j < 4; ++j) {
                        float pv = exp2f(sa[kb2][c * 4 + j] - mnew);
                        rsum += pv;
                        pf[kb2][c][j] = (_Float16)pv;
                    }
        } else {
#pragma unroll
            for (int kb2 = 0; kb2 < 2; ++kb2)
#pragma unroll
                for (int c = 0; c < 4; ++c)
#pragma unroll
                    for (int j = 0; j < 4; ++j) {
                        int key = kt * 64 + kb2 * 32 + j + 8 * c + 4 * q2;
                        float add = allkeep ? 0.f : kb[key];
                        float pv = (key <= q_row) ? exp2f(sa[kb2][c * 4 + j] + add - mnew) : 0.f;
                        rsum += pv;
                        pf[kb2][c][j] = (_Float16)pv;
                    }
        }
        rsum += __shfl_xor(rsum, 32, 64);
        lrow = lrow * alpha + rsum;

        // rescale O
#pragma unroll
        for (int db = 0; db < 2; ++db)
#pragma unroll
            for (int r = 0; r < 16; ++r) oacc[db][r] *= alpha;

        // O^T += V^T·P^T : A = V^T rows (swizzled LDS), B = pf regs
#pragma unroll
        for (int db = 0; db < 2; ++db)
#pragma unroll
            for (int kb2 = 0; kb2 < 2; ++kb2)
#pragma unroll
                for (int c = 0; c < 4; ++c) {
                    int ck = kb2 * 4 + c;                 // 8-key chunk index
                    int seg = ck ^ (l31 & 7);
                    halfx4 va = *(const halfx4*)&Vt[cur][(db * 32 + l31) * 64 + seg * 8 + q2 * 4];
                    oacc[db] = __builtin_amdgcn_mfma_f32_32x32x8f16(va, pf[kb2][c], oacc[db], 0, 0, 0);
                }
    }

    // epilogue: normalize, store O (lane holds col q=l31; rows d per reg map)
    float linv = 1.f / lrow;
    size_t orow = ((size_t)b * T_ + q_row) * D_ + h * HD_;
#pragma unroll
    for (int db = 0; db < 2; ++db)
#pragma unroll
        for (int g = 0; g < 4; ++g) {
            halfx4 ov;
#pragma unroll
            for (int j = 0; j < 4; ++j)
                ov[j] = (_Float16)(oacc[db][g * 4 + j] * linv);
            int d = db * 32 + 8 * g + 4 * q2;
            *(halfx4*)(oh + orow + d) = ov;
        }
}

// ---------------------------------------------------------------------------
extern "C" void kernel_launch(void* const* d_in, const int* in_sizes, int n_in,
                              void* d_out, int out_size, void* d_ws, size_t ws_size,
                              hipStream_t stream)
{
    (void)in_sizes; (void)n_in; (void)out_size; (void)ws_size;
    const float* x     = (const float*)d_in[0];
    const float* mask  = (const float*)d_in[1];
    const float* w_qkv = (const float*)d_in[2];
    const float* b_qkv = (const float*)d_in[3];
    const float* w_out = (const float*)d_in[4];
    const float* b_out = (const float*)d_in[5];
    float* out = (float*)d_out;

    const size_t QKV1 = (size_t)B_ * H_ * T_ * HD_;   // 4M halfs
    _Float16* xh  = (_Float16*)d_ws;                  // 4M
    _Float16* wqh = xh  + (size_t)M_ * K_;            // 3M
    _Float16* woh = wqh + (size_t)N3_ * K_;           // 1M
    _Float16* qh  = woh + (size_t)D_ * K_;            // 4M
    _Float16* kh  = qh  + QKV1;                       // 4M
    _Float16* vth = kh  + QKV1;                       // 4M
    _Float16* oh  = vth + QKV1;                       // 4M
    float* kbias  = (float*)(oh + QKV1);              // 4096 floats
    int* tflags   = (int*)(kbias + (size_t)B_ * T_);  // 64 ints

    f2h_kernel<<<(M_ * K_) / 8 / 256, 256, 0, stream>>>(x, xh, M_ * K_);
    f2h_kernel<<<(N3_ * K_) / 8 / 256, 256, 0, stream>>>(w_qkv, wqh, N3_ * K_);
    f2h_kernel<<<(D_ * K_) / 8 / 256, 256, 0, stream>>>(w_out, woh, D_ * K_);
    initflags_kernel<<<1, 64, 0, stream>>>(tflags);
    mkbias_kernel<<<(B_ * T_ + 255) / 256, 256, 0, stream>>>(mask, kbias, tflags, B_ * T_);

    gemm_qkv<<<dim3(N3_ / 128, M_ / 128), 256, 0, stream>>>(
        xh, wqh, b_qkv, qh, kh, vth);
    attn_kernel<<<dim3(T_ / 128, H_, B_), 256, 0, stream>>>(
        qh, kh, vth, kbias, tflags, oh);
    gemm_out<<<dim3(D_ / 128, M_ / 128), 256, 0, stream>>>(
        oh, woh, b_out, out);
}

// Round 5
// 224.876 us; speedup vs baseline: 5.8933x; 1.0775x over previous
//
#include <hip/hip_runtime.h>
#include <cmath>

#define B_ 2
#define T_ 2048
#define D_ 1024
#define H_ 16
#define HD_ 64
#define M_ (B_ * T_)   // 4096
#define N3_ (3 * D_)   // 3072
#define K_ 1024

typedef _Float16 halfx8 __attribute__((ext_vector_type(8)));
typedef _Float16 halfx4 __attribute__((ext_vector_type(4)));
typedef float f32x4 __attribute__((ext_vector_type(4)));
typedef float f32x16 __attribute__((ext_vector_type(16)));

#define ASYNC_COPY16(gp, lp) \
  __builtin_amdgcn_global_load_lds((__attribute__((address_space(1))) void*)(gp), \
      (__attribute__((address_space(3))) void*)(lp), 16, 0, 0)

// q pre-scale: 1/sqrt(64) * log2(e)  (softmax in exp2 domain)
#define QSCALE 0.1803368801111204f

// chunk tables: 8 key-tiles (512 keys) per chunk; nchunks(qt)=ceil((2qt+2)/8)
// dispatch order: big qt first. CB = slot base per qt (40 slots per (b,h)).
__device__ const int QT_OF[40] = {15,15,15,15, 14,14,14,14, 13,13,13,13, 12,12,12,12,
                                  11,11,11, 10,10,10, 9,9,9, 8,8,8,
                                  7,7, 6,6, 5,5, 4,4, 3, 2, 1, 0};
__device__ const int C_OF[40]  = {0,1,2,3, 0,1,2,3, 0,1,2,3, 0,1,2,3,
                                  0,1,2, 0,1,2, 0,1,2, 0,1,2,
                                  0,1, 0,1, 0,1, 0,1, 0, 0, 0, 0};
__device__ const int CB_OF[16] = {0,1,2,3,4,6,8,10,12,15,18,21,24,28,32,36};
__device__ const int NC_OF[16] = {1,1,1,1,2,2,2,2,3,3,3,3,4,4,4,4};

// ---------------------------------------------------------------------------
__global__ __launch_bounds__(256) void f2h_kernel(const float* __restrict__ s,
                                                  _Float16* __restrict__ d, int n)
{
    int i = (blockIdx.x * 256 + threadIdx.x) * 8;
    if (i >= n) return;
    float4 a = *(const float4*)(s + i);
    float4 b = *(const float4*)(s + i + 4);
    halfx8 h;
    h[0] = (_Float16)a.x; h[1] = (_Float16)a.y; h[2] = (_Float16)a.z; h[3] = (_Float16)a.w;
    h[4] = (_Float16)b.x; h[5] = (_Float16)b.y; h[6] = (_Float16)b.z; h[7] = (_Float16)b.w;
    *(halfx8*)(d + i) = h;
}

// tile flags init (1 = all keys kept in that 64-key tile)
__global__ void initflags_kernel(int* __restrict__ tflags)
{
    tflags[threadIdx.x] = 1;
}

// key-pad mask -> additive bias (0 keep, -inf drop) + per-64-tile flags
__global__ __launch_bounds__(256) void mkbias_kernel(const float* __restrict__ mask,
                                                     float* __restrict__ kbias,
                                                     int* __restrict__ tflags, int n)
{
    int i = blockIdx.x * 256 + threadIdx.x;
    if (i < n) {
        float mv = mask[i];
        kbias[i] = (mv != 0.f) ? 0.f : -INFINITY;
        if (mv == 0.f) tflags[i >> 6] = 0;   // benign race: all writers store 0
    }
}

// ---------------------------------------------------------------------------
// GEMM1: qkv = x @ w_qkv^T + b_qkv (fp16 MFMA, 128x128 tile, BK=32).
// Epilogue: q (scaled) -> [b,h,t,hd]; k -> [b,h,t,hd] with hd-seg XOR-swizzle
// by (t&7); v -> [b,h,hd,t] with t-seg (within 64-tiles) XOR-swizzle by (hd&7).
// ---------------------------------------------------------------------------
__global__ __launch_bounds__(256) void gemm_qkv(
    const _Float16* __restrict__ A, const _Float16* __restrict__ Wt,
    const float* __restrict__ bias,
    _Float16* __restrict__ qh, _Float16* __restrict__ kh, _Float16* __restrict__ vth)
{
    __shared__ _Float16 As[128 * 32];
    __shared__ _Float16 Bs[128 * 32];
    const int tid = threadIdx.x;
    const int lane = tid & 63, w = tid >> 6;
    const int col = lane & 15, quad = lane >> 4;
    const int wr = w >> 1, wc = w & 1;
    const int m0 = blockIdx.y << 7, n0 = blockIdx.x << 7;

    const int c0 = w * 2, c1 = c0 + 1;
    const int r0 = c0 * 16 + (lane >> 2), r1 = c1 * 16 + (lane >> 2);
    const int ks = (lane & 3) << 3;

    f32x4 acc[4][4] = {};

    for (int k0 = 0; k0 < K_; k0 += 32) {
        ASYNC_COPY16(A  + (size_t)(m0 + r0) * K_ + k0 + ks, &As[c0 * 512]);
        ASYNC_COPY16(A  + (size_t)(m0 + r1) * K_ + k0 + ks, &As[c1 * 512]);
        ASYNC_COPY16(Wt + (size_t)(n0 + r0) * K_ + k0 + ks, &Bs[c0 * 512]);
        ASYNC_COPY16(Wt + (size_t)(n0 + r1) * K_ + k0 + ks, &Bs[c1 * 512]);
        __syncthreads();
        halfx8 af[4], bf[4];
#pragma unroll
        for (int i = 0; i < 4; ++i)
            af[i] = *(const halfx8*)&As[(wr * 64 + i * 16 + col) * 32 + quad * 8];
#pragma unroll
        for (int j = 0; j < 4; ++j)
            bf[j] = *(const halfx8*)&Bs[(wc * 64 + j * 16 + col) * 32 + quad * 8];
#pragma unroll
        for (int i = 0; i < 4; ++i)
#pragma unroll
            for (int j = 0; j < 4; ++j)
                acc[i][j] = __builtin_amdgcn_mfma_f32_16x16x32_f16(af[i], bf[j], acc[i][j], 0, 0, 0);
        __syncthreads();
    }

#pragma unroll
    for (int i = 0; i < 4; ++i) {
#pragma unroll
        for (int r = 0; r < 4; ++r) {
            int m = m0 + wr * 64 + i * 16 + quad * 4 + r;
            int bb = m >> 11, tt = m & (T_ - 1);
#pragma unroll
            for (int j = 0; j < 4; ++j) {
                int n = n0 + wc * 64 + j * 16 + col;
                float val = acc[i][j][r] + bias[n];
                int which = n >> 10, head = (n >> 6) & 15, dd = n & 63;
                if (which == 0) {
                    qh[((size_t)(bb * H_ + head) * T_ + tt) * HD_ + dd] = (_Float16)(val * QSCALE);
                } else if (which == 1) {
                    int dds = ((((dd >> 3) ^ (tt & 7)) & 7) << 3) | (dd & 7);
                    kh[((size_t)(bb * H_ + head) * T_ + tt) * HD_ + dds] = (_Float16)val;
                } else {
                    int tts = (tt & ~63) | (((((tt >> 3) & 7) ^ (dd & 7)) & 7) << 3) | (tt & 7);
                    vth[((size_t)(bb * H_ + head) * HD_ + dd) * T_ + tts] = (_Float16)val;
                }
            }
        }
    }
}

// ---------------------------------------------------------------------------
// GEMM2: out = attn_out @ w_out^T + b_out (fp32 output)
// ---------------------------------------------------------------------------
__global__ __launch_bounds__(256) void gemm_out(
    const _Float16* __restrict__ A, const _Float16* __restrict__ Wt,
    const float* __restrict__ bias, float* __restrict__ C)
{
    __shared__ _Float16 As[128 * 32];
    __shared__ _Float16 Bs[128 * 32];
    const int tid = threadIdx.x;
    const int lane = tid & 63, w = tid >> 6;
    const int col = lane & 15, quad = lane >> 4;
    const int wr = w >> 1, wc = w & 1;
    const int m0 = blockIdx.y << 7, n0 = blockIdx.x << 7;

    const int c0 = w * 2, c1 = c0 + 1;
    const int r0 = c0 * 16 + (lane >> 2), r1 = c1 * 16 + (lane >> 2);
    const int ks = (lane & 3) << 3;

    f32x4 acc[4][4] = {};

    for (int k0 = 0; k0 < K_; k0 += 32) {
        ASYNC_COPY16(A  + (size_t)(m0 + r0) * K_ + k0 + ks, &As[c0 * 512]);
        ASYNC_COPY16(A  + (size_t)(m0 + r1) * K_ + k0 + ks, &As[c1 * 512]);
        ASYNC_COPY16(Wt + (size_t)(n0 + r0) * K_ + k0 + ks, &Bs[c0 * 512]);
        ASYNC_COPY16(Wt + (size_t)(n0 + r1) * K_ + k0 + ks, &Bs[c1 * 512]);
        __syncthreads();
        halfx8 af[4], bf[4];
#pragma unroll
        for (int i = 0; i < 4; ++i)
            af[i] = *(const halfx8*)&As[(wr * 64 + i * 16 + col) * 32 + quad * 8];
#pragma unroll
        for (int j = 0; j < 4; ++j)
            bf[j] = *(const halfx8*)&Bs[(wc * 64 + j * 16 + col) * 32 + quad * 8];
#pragma unroll
        for (int i = 0; i < 4; ++i)
#pragma unroll
            for (int j = 0; j < 4; ++j)
                acc[i][j] = __builtin_amdgcn_mfma_f32_16x16x32_f16(af[i], bf[j], acc[i][j], 0, 0, 0);
        __syncthreads();
    }

#pragma unroll
    for (int i = 0; i < 4; ++i) {
#pragma unroll
        for (int r = 0; r < 4; ++r) {
            int m = m0 + wr * 64 + i * 16 + quad * 4 + r;
#pragma unroll
            for (int j = 0; j < 4; ++j) {
                int n = n0 + wc * 64 + j * 16 + col;
                C[(size_t)m * D_ + n] = acc[i][j][r] + bias[n];
            }
        }
    }
}

// ---------------------------------------------------------------------------
// Flash attention v5: flash-decoding key-split over transposed-S scheme.
// Block = (qt,chunk) pair: 128 q-rows x 8 key-tiles (512 keys), 4 waves x
// 32 q-rows. Writes unnormalized partials (m, l fp32; O^T fp16) per chunk;
// attn_combine merges <=4 chunks/row. 1280 uniform blocks -> ~5 blocks/CU.
// ---------------------------------------------------------------------------
__global__ __launch_bounds__(256) void attn_kernel(
    const _Float16* __restrict__ qh, const _Float16* __restrict__ kh,
    const _Float16* __restrict__ vth, const float* __restrict__ kbias,
    const int* __restrict__ tflags,
    float* __restrict__ pm, float* __restrict__ pl, _Float16* __restrict__ po)
{
    __shared__ _Float16 Ks[2][64 * 64];
    __shared__ _Float16 Vt[2][64 * 64];

    const int xi = blockIdx.x;
    const int qt = QT_OF[xi], c = C_OF[xi];
    const int h = blockIdx.y, b = blockIdx.z;
    const int tid = threadIdx.x;
    const int lane = tid & 63, w = tid >> 6;
    const int l31 = lane & 31, q2 = lane >> 5;

    const int kt0 = c * 8;
    const int ktend = min(2 * qt + 1, kt0 + 7);

    const size_t hb = (size_t)(b * H_ + h);
    const _Float16* qp = qh + hb * T_ * HD_;
    const _Float16* kp = kh + hb * T_ * HD_;
    const _Float16* vp = vth + hb * HD_ * T_;
    const float* kb = kbias + (size_t)b * T_;
    const int* tf = tflags + b * 32;

    const int q_row = qt * 128 + w * 32 + l31;   // this lane's query row

    // Q B-frags (global, unswizzled): B[n=q=lane&31][k=hc*16+q2*8+j]
    halfx8 bq[4];
#pragma unroll
    for (int hc = 0; hc < 4; ++hc)
        bq[hc] = *(const halfx8*)(qp + (size_t)q_row * HD_ + hc * 16 + q2 * 8);

    float mrow = -INFINITY, lrow = 0.f;
    f32x16 oacc[2] = {};

    // prologue: stage tile kt0 into buffer 0
    {
        const _Float16* ksrc = kp + (size_t)(kt0 * 64 + w * 16) * HD_;
        ASYNC_COPY16(ksrc + lane * 8, &Ks[0][(w * 16) * 64]);
        ASYNC_COPY16(ksrc + 8 * HD_ + lane * 8, &Ks[0][(w * 16 + 8) * 64]);
        const _Float16* vsrc = vp + (size_t)(w * 16 + (lane >> 3)) * T_
                                 + kt0 * 64 + (lane & 7) * 8;
        ASYNC_COPY16(vsrc, &Vt[0][(w * 16) * 64]);
        ASYNC_COPY16(vsrc + 8 * T_, &Vt[0][(w * 16 + 8) * 64]);
    }

    for (int kt = kt0; kt <= ktend; ++kt) {
        const int cur = (kt - kt0) & 1;
        __syncthreads();   // drains async copies for tile kt
        if (kt < ktend) {  // prefetch next tile into other buffer
            const int nb = cur ^ 1;
            const _Float16* ksrc = kp + (size_t)((kt + 1) * 64 + w * 16) * HD_;
            ASYNC_COPY16(ksrc + lane * 8, &Ks[nb][(w * 16) * 64]);
            ASYNC_COPY16(ksrc + 8 * HD_ + lane * 8, &Ks[nb][(w * 16 + 8) * 64]);
            const _Float16* vsrc = vp + (size_t)(w * 16 + (lane >> 3)) * T_
                                     + (kt + 1) * 64 + (lane & 7) * 8;
            ASYNC_COPY16(vsrc, &Vt[nb][(w * 16) * 64]);
            ASYNC_COPY16(vsrc + 8 * T_, &Vt[nb][(w * 16 + 8) * 64]);
        }
        // wave-uniform: no valid keys for this wave's q-strip -> skip compute
        if (kt * 64 > qt * 128 + w * 32 + 31) continue;

        // S^T = K·Q^T : A = K rows (swizzled LDS), B = Q regs
        f32x16 sa[2];
#pragma unroll
        for (int kb2 = 0; kb2 < 2; ++kb2) {
            f32x16 a;
#pragma unroll
            for (int r = 0; r < 16; ++r) a[r] = 0.f;
#pragma unroll
            for (int hc = 0; hc < 4; ++hc) {
                int seg = (hc * 2 + q2) ^ (l31 & 7);
                halfx8 ka = *(const halfx8*)&Ks[cur][(kb2 * 32 + l31) * 64 + seg * 8];
                a = __builtin_amdgcn_mfma_f32_32x32x16_f16(ka, bq[hc], a, 0, 0, 0);
            }
            sa[kb2] = a;
        }

        // running max on raw scores (upper bound; bias only 0/-inf)
        float mx = sa[0][0];
#pragma unroll
        for (int r = 1; r < 16; ++r) mx = fmaxf(mx, sa[0][r]);
#pragma unroll
        for (int r = 0; r < 16; ++r) mx = fmaxf(mx, sa[1][r]);
        mx = fmaxf(mx, __shfl_xor(mx, 32, 64));
        float mnew = fmaxf(mrow, mx);
        float alpha = exp2f(mrow - mnew);
        mrow = mnew;

        // P = exp2(s [+bias] - m), packed straight into 32x32x8 B-frags
        const bool interior = (kt * 64 + 63 <= qt * 128 + w * 32);  // wave-uniform
        const int allkeep = tf[kt];
        halfx4 pf[2][4];
        float rsum = 0.f;
        if (interior && allkeep) {
#pragma unroll
            for (int kb2 = 0; kb2 < 2; ++kb2)
#pragma unroll
                for (int cc = 0; cc < 4; ++cc)
#pragma unroll
                    for (int j = 0; j < 4; ++j) {
                        float pv = exp2f(sa[kb2][cc * 4 + j] - mnew);
                        rsum += pv;
                        pf[kb2][cc][j] = (_Float16)pv;
                    }
        } else {
#pragma unroll
            for (int kb2 = 0; kb2 < 2; ++kb2)
#pragma unroll
                for (int cc = 0; cc < 4; ++cc)
#pragma unroll
                    for (int j = 0; j < 4; ++j) {
                        int key = kt * 64 + kb2 * 32 + j + 8 * cc + 4 * q2;
                        float add = allkeep ? 0.f : kb[key];
                        float pv = (key <= q_row) ? exp2f(sa[kb2][cc * 4 + j] + add - mnew) : 0.f;
                        rsum += pv;
                        pf[kb2][cc][j] = (_Float16)pv;
                    }
        }
        rsum += __shfl_xor(rsum, 32, 64);
        lrow = lrow * alpha + rsum;

        // rescale O
#pragma unroll
        for (int db = 0; db < 2; ++db)
#pragma unroll
            for (int r = 0; r < 16; ++r) oacc[db][r] *= alpha;

        // O^T += V^T·P^T : A = V^T rows (swizzled LDS), B = pf regs
#pragma unroll
        for (int db = 0; db < 2; ++db)
#pragma unroll
            for (int kb2 = 0; kb2 < 2; ++kb2)
#pragma unroll
                for (int cc = 0; cc < 4; ++cc) {
                    int ck = kb2 * 4 + cc;                // 8-key chunk index
                    int seg = ck ^ (l31 & 7);
                    halfx4 va = *(const halfx4*)&Vt[cur][(db * 32 + l31) * 64 + seg * 8 + q2 * 4];
                    oacc[db] = __builtin_amdgcn_mfma_f32_32x32x8f16(va, pf[kb2][cc], oacc[db], 0, 0, 0);
                }
    }

    // epilogue: write partials (m, l fp32; O^T fp16, unnormalized)
    const int slot = (int)hb * 40 + CB_OF[qt] + c;
    const int qloc = w * 32 + l31;
    if (q2 == 0) {
        pm[(size_t)slot * 128 + qloc] = mrow;
        pl[(size_t)slot * 128 + qloc] = lrow;
    }
    _Float16* pob = po + ((size_t)slot * 128 + qloc) * 64;
#pragma unroll
    for (int db = 0; db < 2; ++db)
#pragma unroll
        for (int g = 0; g < 4; ++g) {
            halfx4 ov;
#pragma unroll
            for (int j = 0; j < 4; ++j)
                ov[j] = (_Float16)(oacc[db][g * 4 + j]);
            *(halfx4*)(pob + db * 32 + 8 * g + 4 * q2) = ov;
        }
}

// ---------------------------------------------------------------------------
// Combine partials: block per (qt, h, b); thread = (row r, d-half).
// O = sum_c exp2(m_c - m*) O_c / (sum_c exp2(m_c - m*) l_c)
// ---------------------------------------------------------------------------
__global__ __launch_bounds__(256) void attn_combine(
    const float* __restrict__ pm, const float* __restrict__ pl,
    const _Float16* __restrict__ po, _Float16* __restrict__ oh)
{
    const int qt = blockIdx.x, h = blockIdx.y, b = blockIdx.z;
    const int nc = NC_OF[qt], cb = CB_OF[qt];
    const int bh = b * H_ + h;
    const int tid = threadIdx.x;
    const int r = tid >> 1, dh = tid & 1;

    const int slot0 = bh * 40 + cb;
    float mc[4], lc[4];
    float mstar = -INFINITY;
    for (int cc = 0; cc < nc; ++cc) {
        mc[cc] = pm[(size_t)(slot0 + cc) * 128 + r];
        lc[cc] = pl[(size_t)(slot0 + cc) * 128 + r];
        mstar = fmaxf(mstar, mc[cc]);
    }
    float lstar = 0.f, wc[4];
    for (int cc = 0; cc < nc; ++cc) {
        wc[cc] = exp2f(mc[cc] - mstar);
        lstar += wc[cc] * lc[cc];
    }
    float acc[32] = {};
    for (int cc = 0; cc < nc; ++cc) {
        const _Float16* src = po + ((size_t)(slot0 + cc) * 128 + r) * 64 + dh * 32;
        float wv = wc[cc];
#pragma unroll
        for (int g = 0; g < 4; ++g) {
            halfx8 hv = *(const halfx8*)(src + g * 8);
#pragma unroll
            for (int j = 0; j < 8; ++j)
                acc[g * 8 + j] += wv * (float)hv[j];
        }
    }
    float linv = 1.f / lstar;
    _Float16* dst = oh + ((size_t)(b * T_ + qt * 128 + r)) * D_ + h * 64 + dh * 32;
#pragma unroll
    for (int g = 0; g < 4; ++g) {
        halfx8 ov;
#pragma unroll
        for (int j = 0; j < 8; ++j)
            ov[j] = (_Float16)(acc[g * 8 + j] * linv);
        *(halfx8*)(dst + g * 8) = ov;
    }
}

// ---------------------------------------------------------------------------
extern "C" void kernel_launch(void* const* d_in, const int* in_sizes, int n_in,
                              void* d_out, int out_size, void* d_ws, size_t ws_size,
                              hipStream_t stream)
{
    (void)in_sizes; (void)n_in; (void)out_size; (void)ws_size;
    const float* x     = (const float*)d_in[0];
    const float* mask  = (const float*)d_in[1];
    const float* w_qkv = (const float*)d_in[2];
    const float* b_qkv = (const float*)d_in[3];
    const float* w_out = (const float*)d_in[4];
    const float* b_out = (const float*)d_in[5];
    float* out = (float*)d_out;

    const size_t QKV1 = (size_t)B_ * H_ * T_ * HD_;   // 4M halfs
    _Float16* xh  = (_Float16*)d_ws;                  // 4.2M halfs
    _Float16* wqh = xh  + (size_t)M_ * K_;            // 3.1M
    _Float16* woh = wqh + (size_t)N3_ * K_;           // 1.0M
    _Float16* qh  = woh + (size_t)D_ * K_;            // 4.2M
    _Float16* kh  = qh  + QKV1;
    _Float16* vth = kh  + QKV1;
    _Float16* oh  = vth + QKV1;
    _Float16* po  = oh  + QKV1;                       // 1280*128*64 = 10.5M halfs
    float* kbias  = (float*)(po + (size_t)1280 * 128 * 64);
    float* pm     = kbias + (size_t)B_ * T_;          // 1280*128 floats
    float* pl     = pm + (size_t)1280 * 128;
    int* tflags   = (int*)(pl + (size_t)1280 * 128);  // 64 ints

    f2h_kernel<<<(M_ * K_) / 8 / 256, 256, 0, stream>>>(x, xh, M_ * K_);
    f2h_kernel<<<(N3_ * K_) / 8 / 256, 256, 0, stream>>>(w_qkv, wqh, N3_ * K_);
    f2h_kernel<<<(D_ * K_) / 8 / 256, 256, 0, stream>>>(w_out, woh, D_ * K_);
    initflags_kernel<<<1, 64, 0, stream>>>(tflags);
    mkbias_kernel<<<(B_ * T_ + 255) / 256, 256, 0, stream>>>(mask, kbias, tflags, B_ * T_);

    gemm_qkv<<<dim3(N3_ / 128, M_ / 128), 256, 0, stream>>>(
        xh, wqh, b_qkv, qh, kh, vth);
    attn_kernel<<<dim3(40, H_, B_), 256, 0, stream>>>(
        qh, kh, vth, kbias, tflags, pm, pl, po);
    attn_combine<<<dim3(T_ / 128, H_, B_), 256, 0, stream>>>(
        pm, pl, po, oh);
    gemm_out<<<dim3(D_ / 128, M_ / 128), 256, 0, stream>>>(
        oh, woh, b_out, out);
}